// Round 4
// baseline (1037.896 us; speedup 1.0000x reference)
//
#include <hip/hip_runtime.h>

using short8  = short     __attribute__((ext_vector_type(8)));
using half2v  = _Float16  __attribute__((ext_vector_type(2)));
using half4   = _Float16  __attribute__((ext_vector_type(4)));
using float2_ = float     __attribute__((ext_vector_type(2)));
using float4_ = float     __attribute__((ext_vector_type(4)));

__device__ __forceinline__ unsigned short f2bf(float f) {
  union { float f; unsigned u; } v; v.f = f;
  unsigned r = v.u + 0x7fffu + ((v.u >> 16) & 1u);
  return (unsigned short)(r >> 16);
}
// force a (wave-uniform) value into an SGPR
__device__ __forceinline__ float sgprf(float x) {
  return __int_as_float(__builtin_amdgcn_readfirstlane(__float_as_int(x)));
}
// packed f32x2 -> f16x2 (v_cvt_pkrtz_f16_f32), bit-cast to our half2v
__device__ __forceinline__ half2v pkrtz(float a, float b) {
  return __builtin_bit_cast(half2v, __builtin_amdgcn_cvt_pkrtz(a, b));
}

// ---------------- LayerNorm: x fp32 (8192x512) -> xn bf16 ----------------
__global__ __launch_bounds__(256, 4) void ln_kernel(
    const float* __restrict__ x, const float* __restrict__ gamma,
    const float* __restrict__ beta, unsigned short* __restrict__ xn) {
  int w = threadIdx.x >> 6, lane = threadIdx.x & 63;
  int row = blockIdx.x * 4 + w;
  const float4_* xr = (const float4_*)(x + row * 512);
  float4_ v0 = xr[lane * 2], v1 = xr[lane * 2 + 1];
  float s = 0.f, ss = 0.f;
#pragma unroll
  for (int e = 0; e < 4; ++e) { s += v0[e] + v1[e]; ss += v0[e]*v0[e] + v1[e]*v1[e]; }
#pragma unroll
  for (int off = 1; off < 64; off <<= 1) { s += __shfl_xor(s, off); ss += __shfl_xor(ss, off); }
  float mu = s * (1.f/512.f);
  float var = ss * (1.f/512.f) - mu*mu;
  float rs = rsqrtf(var + 1e-5f);
  const float4_* gp = (const float4_*)gamma;
  const float4_* bp = (const float4_*)beta;
  float4_ g0 = gp[lane*2], g1 = gp[lane*2+1], b0 = bp[lane*2], b1 = bp[lane*2+1];
  short8 pk;
#pragma unroll
  for (int e = 0; e < 4; ++e) {
    pk[e]   = (short)f2bf((v0[e]-mu)*rs*g0[e] + b0[e]);
    pk[e+4] = (short)f2bf((v1[e]-mu)*rs*g1[e] + b1[e]);
  }
  *(short8*)&xn[row*512 + lane*8] = pk;
}

// ------------- weights fp32 -> bf16 transposed + mix_post packed-half2 table -------
__global__ __launch_bounds__(256, 4) void wconv(
    const float* __restrict__ Wq, const float* __restrict__ Wkv,
    const float* __restrict__ Wout, const float* __restrict__ mixq,
    unsigned short* __restrict__ wt, unsigned short* __restrict__ wot,
    unsigned int* __restrict__ mqp) {
  int t = blockIdx.x * 256 + threadIdx.x;
  if (t < 786432) {
    int k = t / 1536, n = t % 1536;
    float v = (n < 512) ? Wq[k*512 + n] * 0.125f : Wkv[k*1024 + (n - 512)];
    wt[n*512 + k] = f2bf(v);
  } else if (t < 1048576) {
    int t2 = t - 786432;
    int k = t2 >> 9, n = t2 & 511;
    wot[n*512 + k] = f2bf(Wout[k*512 + n]);
  } else if (t < 1048608) {
    // mqp[gp*4 + p] = half2(mixq[gp][2p], mixq[gp][2p+1])  (gp = premixed head)
    int idx = t - 1048576;        // 0..31
    int gp = idx >> 2, p = idx & 3;
    _Float16 lo = (_Float16)mixq[gp*8 + 2*p];
    _Float16 hi = (_Float16)mixq[gp*8 + 2*p + 1];
    unsigned short lb = *(unsigned short*)&lo, hb = *(unsigned short*)&hi;
    mqp[idx] = (unsigned)lb | ((unsigned)hb << 16);
  }
}

// ---------------- QKV GEMM: xn(8192x512) @ Wt^T -> Q,K (bf16 b,h,n,64), V^T (f16 b,h,64,n)
__global__ __launch_bounds__(256, 2) void qkv_gemm(
    const unsigned short* __restrict__ A, const unsigned short* __restrict__ Bt,
    unsigned short* __restrict__ Qs, unsigned short* __restrict__ Kb,
    _Float16* __restrict__ Vt) {
  __shared__ unsigned short lA[128*32];
  __shared__ unsigned short lB[128*32];
  int bid = blockIdx.x;
  int tm = bid & 63, tn = bid >> 6;           // 64 x 12
  int m0 = tm * 128, n0 = tn * 128;
  int tid = threadIdx.x, lane = tid & 63, w = tid >> 6;
  int lrow = lane & 15, lgrp = lane >> 4;
  int wr = w >> 1, wc = w & 1;
  int r0 = tid >> 2, c0 = tid & 3;
  float4_ acc[4][4];
#pragma unroll
  for (int mi = 0; mi < 4; ++mi)
#pragma unroll
    for (int ni = 0; ni < 4; ++ni) acc[mi][ni] = (float4_){0.f,0.f,0.f,0.f};

  for (int k0 = 0; k0 < 512; k0 += 32) {
    short8 a0 = *(const short8*)&A[(m0 + r0)*512 + k0 + c0*8];
    short8 a1 = *(const short8*)&A[(m0 + 64 + r0)*512 + k0 + c0*8];
    short8 b0 = *(const short8*)&Bt[(n0 + r0)*512 + k0 + c0*8];
    short8 b1 = *(const short8*)&Bt[(n0 + 64 + r0)*512 + k0 + c0*8];
    __syncthreads();
    *(short8*)&lA[tid*8] = a0; *(short8*)&lA[(tid+256)*8] = a1;
    *(short8*)&lB[tid*8] = b0; *(short8*)&lB[(tid+256)*8] = b1;
    __syncthreads();
    short8 af[4], bfr[4];
#pragma unroll
    for (int mi = 0; mi < 4; ++mi) af[mi]  = *(const short8*)&lA[(wr*64 + mi*16 + lrow)*32 + lgrp*8];
#pragma unroll
    for (int ni = 0; ni < 4; ++ni) bfr[ni] = *(const short8*)&lB[(wc*64 + ni*16 + lrow)*32 + lgrp*8];
#pragma unroll
    for (int mi = 0; mi < 4; ++mi)
#pragma unroll
      for (int ni = 0; ni < 4; ++ni)
        acc[mi][ni] = __builtin_amdgcn_mfma_f32_16x16x32_bf16(af[mi], bfr[ni], acc[mi][ni], 0, 0, 0);
  }
#pragma unroll
  for (int mi = 0; mi < 4; ++mi) {
#pragma unroll
    for (int ni = 0; ni < 4; ++ni) {
      int col = n0 + wc*64 + ni*16 + lrow;
#pragma unroll
      for (int r = 0; r < 4; ++r) {
        int row = m0 + wr*64 + mi*16 + lgrp*4 + r;
        float v = acc[mi][ni][r];
        int b = row >> 11, i = row & 2047;
        if (col < 1024) {
          unsigned short* dst = (col < 512) ? Qs : Kb;
          int c = col & 511;
          dst[(((b<<3) + (c>>6))*2048 + i)*64 + (c & 63)] = f2bf(v);
        } else {
          int c = col - 1024;
          Vt[(((b<<3) + (c>>6))*64 + (c & 63))*2048 + i] = (_Float16)v;
        }
      }
    }
  }
}

// Stage Q-tile (8h x 16i x 64d bf16) into LDS, chunked [h][c][i] (c = d/8) so that
// MFMA B-frag reads (16 lanes stride 16B) are bank-conflict-free.
__device__ __forceinline__ void stage_q(const unsigned short* __restrict__ Qs,
                                        unsigned short* qlds, int b, int i0, int tid) {
#pragma unroll
  for (int q = 0; q < 4; ++q) {
    int idx = q*256 + tid;                 // 1024 chunks: ((h*16+i)*8 + c)
    int h = idx >> 7, i = (idx >> 3) & 15, c = idx & 7;
    short8 v = *(const short8*)&Qs[(((b<<3)+h)*2048 + i0 + i)*64 + c*8];
    *(short8*)&qlds[((h*8 + c)*16 + i)*8] = v;
  }
}

// ---------------- attn pass 1: softmax stats (m,l) per (i, premixed-head g) ----------
// grid 1024 = 128 i-tiles x (b, j-half) ; 4 waves split the j-half 4-way.
__global__ __launch_bounds__(256, 4) void attn1(
    const unsigned short* __restrict__ Qs, const unsigned short* __restrict__ Kb,
    const float* __restrict__ mixp, float* __restrict__ ml) {
  __shared__ unsigned short qlds[8192];
  __shared__ float Lm[4][8][16], Ll[4][8][16];
  int bid = blockIdx.x;
  int xcd = bid & 7, b = xcd >> 1, jh = xcd & 1, it = bid >> 3;   // XCD-local (b,jh)
  int i0 = it << 4;
  int tid = threadIdx.x, w = tid >> 6, lane = tid & 63;
  int lrow = lane & 15, lgrp = lane >> 4;

  float mp[64];                               // mix_pre -> SGPRs
#pragma unroll
  for (int k = 0; k < 64; ++k) mp[k] = sgprf(mixp[k]);

  stage_q(Qs, qlds, b, i0, tid);
  __syncthreads();

  float m_[8], l_[8];
#pragma unroll
  for (int g = 0; g < 8; ++g) { m_[g] = -1e30f; l_[g] = 0.f; }

  for (int t = 0; t < 16; ++t) {
    int jt = (jh << 6) + w + (t << 2);
    int j0 = jt << 4;
    float4_ S[8];
#pragma unroll
    for (int hb = 0; hb < 2; ++hb) {
      short8 kf[4][2];
#pragma unroll
      for (int hh = 0; hh < 4; ++hh) {
        const unsigned short* kp = &Kb[(((b<<3)+hb*4+hh)*2048 + j0 + lrow)*64 + lgrp*8];
        kf[hh][0] = *(const short8*)kp;
        kf[hh][1] = *(const short8*)(kp + 32);
      }
#pragma unroll
      for (int hh = 0; hh < 4; ++hh) {
        int h = hb*4 + hh;
        short8 q0 = *(const short8*)&qlds[((h*8 + lgrp)*16 + lrow)*8];
        short8 q1 = *(const short8*)&qlds[((h*8 + lgrp + 4)*16 + lrow)*8];
        float4_ z = {0.f,0.f,0.f,0.f};
        z = __builtin_amdgcn_mfma_f32_16x16x32_bf16(kf[hh][0], q0, z, 0, 0, 0);
        S[h] = __builtin_amdgcn_mfma_f32_16x16x32_bf16(kf[hh][1], q1, z, 0, 0, 0);
      }
    }
    // premix (packed f32) + online stats
#pragma unroll
    for (int g = 0; g < 8; ++g) {
      float2_ sa = (float2_){S[0][0], S[0][1]} * mp[g];
      float2_ sb = (float2_){S[0][2], S[0][3]} * mp[g];
#pragma unroll
      for (int h = 1; h < 8; ++h) {
        float m = mp[h*8 + g];
        sa += (float2_){S[h][0], S[h][1]} * m;
        sb += (float2_){S[h][2], S[h][3]} * m;
      }
      float tm = fmaxf(fmaxf(sa[0], sa[1]), fmaxf(sb[0], sb[1]));
      float mn = fmaxf(m_[g], tm);
      l_[g] = l_[g]*__expf(m_[g]-mn) + __expf(sa[0]-mn) + __expf(sa[1]-mn)
            + __expf(sb[0]-mn) + __expf(sb[1]-mn);
      m_[g] = mn;
    }
  }
  // merge across lane-groups (disjoint j)
#pragma unroll
  for (int g = 0; g < 8; ++g) {
#pragma unroll
    for (int off = 16; off < 64; off <<= 1) {
      float om = __shfl_xor(m_[g], off);
      float ol = __shfl_xor(l_[g], off);
      float mn = fmaxf(m_[g], om);
      l_[g] = l_[g]*__expf(m_[g]-mn) + ol*__expf(om-mn);
      m_[g] = mn;
    }
  }
  if (lgrp == 0) {
#pragma unroll
    for (int g = 0; g < 8; ++g) { Lm[w][g][lrow] = m_[g]; Ll[w][g][lrow] = l_[g]; }
  }
  __syncthreads();
  if (w == 0 && lgrp == 0) {
    int gi = b*2048 + i0 + lrow;
#pragma unroll
    for (int g = 0; g < 8; ++g) {
      float M = Lm[0][g][lrow], L = Ll[0][g][lrow];
#pragma unroll
      for (int wv = 1; wv < 4; ++wv) {
        float om = Lm[wv][g][lrow], ol = Ll[wv][g][lrow];
        float mn = fmaxf(M, om);
        L = L*__expf(M-mn) + ol*__expf(om-mn); M = mn;
      }
      ml[((jh*8192 + gi)*8 + g)*2]     = M;
      ml[((jh*8192 + gi)*8 + g)*2 + 1] = L;
    }
  }
}

// ---------------- merge the two j-halves -> exact normalizer mm = M + log L --------
__global__ __launch_bounds__(256, 8) void attn1m(const float* __restrict__ ml,
                                                 float* __restrict__ mm) {
  int idx = blockIdx.x*256 + threadIdx.x;     // 65536 = (b,i,g)
  float m0 = ml[idx*2], l0 = ml[idx*2+1];
  float m1 = ml[(65536+idx)*2], l1 = ml[(65536+idx)*2+1];
  float M = fmaxf(m0, m1);
  float L = l0*__expf(m0-M) + l1*__expf(m1-M);
  mm[idx] = M + __logf(L);
}

// ---------------- attn pass 2: recompute, normalize, postmix (f16), PV --------------
// grid 1024 = 128 i-tiles x (b, g-half) ; 4 waves split full-j 4-way -> non-atomic out.
__global__ __launch_bounds__(256, 3) void attn2(
    const unsigned short* __restrict__ Qs, const unsigned short* __restrict__ Kb,
    const _Float16* __restrict__ Vt, const float* __restrict__ mixp,
    const unsigned int* __restrict__ mqp, const float* __restrict__ mm,
    unsigned short* __restrict__ AO) {
  __shared__ unsigned short qlds[8192];
  __shared__ float Ob[4][64][16];
  int bid = blockIdx.x;
  int xcd = bid & 7, b = xcd >> 1, gh = xcd & 1, it = bid >> 3;
  int i0 = it << 4;
  int tid = threadIdx.x, w = tid >> 6, lane = tid & 63;
  int lrow = lane & 15, lgrp = lane >> 4;

  float mp[64];
#pragma unroll
  for (int k = 0; k < 64; ++k) mp[k] = sgprf(mixp[k]);
  half2v mq2[8][2];                           // mix_post pairs for my 4 output heads
#pragma unroll
  for (int gp = 0; gp < 8; ++gp)
#pragma unroll
    for (int p = 0; p < 2; ++p) {
      unsigned u = mqp[gp*4 + gh*2 + p];
      mq2[gp][p] = __builtin_bit_cast(half2v, u);
    }

  stage_q(Qs, qlds, b, i0, tid);
  float mmr[8];
  int gi = b*2048 + i0 + lrow;
#pragma unroll
  for (int g = 0; g < 8; ++g) mmr[g] = mm[gi*8 + g];
  __syncthreads();

  float4_ ot[4][4];
#pragma unroll
  for (int g = 0; g < 4; ++g)
#pragma unroll
    for (int dt = 0; dt < 4; ++dt) ot[g][dt] = (float4_){0.f,0.f,0.f,0.f};

  for (int t = 0; t < 32; ++t) {
    int jt = w + (t << 2);
    int j0 = jt << 4;
    float4_ S[8];
#pragma unroll
    for (int hb = 0; hb < 4; ++hb) {          // 2 heads at a time (reg-lean)
      short8 kf[2][2];
#pragma unroll
      for (int hh = 0; hh < 2; ++hh) {
        const unsigned short* kp = &Kb[(((b<<3)+hb*2+hh)*2048 + j0 + lrow)*64 + lgrp*8];
        kf[hh][0] = *(const short8*)kp;
        kf[hh][1] = *(const short8*)(kp + 32);
      }
#pragma unroll
      for (int hh = 0; hh < 2; ++hh) {
        int h = hb*2 + hh;
        short8 q0 = *(const short8*)&qlds[((h*8 + lgrp)*16 + lrow)*8];
        short8 q1 = *(const short8*)&qlds[((h*8 + lgrp + 4)*16 + lrow)*8];
        float4_ z = {0.f,0.f,0.f,0.f};
        z = __builtin_amdgcn_mfma_f32_16x16x32_bf16(kf[hh][0], q0, z, 0, 0, 0);
        S[h] = __builtin_amdgcn_mfma_f32_16x16x32_bf16(kf[hh][1], q1, z, 0, 0, 0);
      }
    }
    // premix(f32 packed) -> exact softmax -> postmix folded in g'-loop (f16 packed)
    half2v agv[4][2];
#pragma unroll
    for (int r = 0; r < 4; ++r) { agv[r][0] = (half2v)0; agv[r][1] = (half2v)0; }
#pragma unroll
    for (int g = 0; g < 8; ++g) {
      float2_ sa = (float2_){S[0][0], S[0][1]} * mp[g];
      float2_ sb = (float2_){S[0][2], S[0][3]} * mp[g];
#pragma unroll
      for (int h = 1; h < 8; ++h) {
        float m = mp[h*8 + g];
        sa += (float2_){S[h][0], S[h][1]} * m;
        sb += (float2_){S[h][2], S[h][3]} * m;
      }
      float p0 = __expf(sa[0]-mmr[g]), p1 = __expf(sa[1]-mmr[g]);
      float p2 = __expf(sb[0]-mmr[g]), p3 = __expf(sb[1]-mmr[g]);
      half2v d0 = pkrtz(p0, p0);
      half2v d1 = pkrtz(p1, p1);
      half2v d2 = pkrtz(p2, p2);
      half2v d3 = pkrtz(p3, p3);
      agv[0][0] += d0*mq2[g][0]; agv[0][1] += d0*mq2[g][1];
      agv[1][0] += d1*mq2[g][0]; agv[1][1] += d1*mq2[g][1];
      agv[2][0] += d2*mq2[g][0]; agv[2][1] += d2*mq2[g][1];
      agv[3][0] += d3*mq2[g][0]; agv[3][1] += d3*mq2[g][1];
    }
    // transpose (j-rows x g-pairs) -> B-frags per local g, then PV
    half4 pb[4];
#pragma unroll
    for (int g = 0; g < 4; ++g) {
#pragma unroll
      for (int r = 0; r < 4; ++r) pb[g][r] = agv[r][g >> 1][g & 1];
    }
#pragma unroll
    for (int g = 0; g < 4; ++g) {
      const _Float16* vb = &Vt[(((b<<3) + gh*4 + g)*64 + lrow)*2048 + j0 + lgrp*4];
#pragma unroll
      for (int dt = 0; dt < 4; ++dt) {
        half4 vf = *(const half4*)&vb[dt*16*2048];
        ot[g][dt] = __builtin_amdgcn_mfma_f32_16x16x16f16(vf, pb[g], ot[g][dt], 0, 0, 0);
      }
    }
  }
  // merge the 4 waves (disjoint j) in LDS, then write bf16 (exclusive owner)
#pragma unroll
  for (int wv = 0; wv < 4; ++wv) {
    if (w == wv) {
#pragma unroll
      for (int g = 0; g < 4; ++g)
#pragma unroll
        for (int dt = 0; dt < 4; ++dt)
#pragma unroll
          for (int r = 0; r < 4; ++r) {
            int d = dt*16 + lgrp*4 + r;
            if (wv == 0) Ob[g][d][lrow] = ot[g][dt][r];
            else         Ob[g][d][lrow] += ot[g][dt][r];
          }
    }
    __syncthreads();
  }
  int i = tid >> 4, cc = tid & 15;
  unsigned short* dst = &AO[(b*2048 + i0 + i)*512 + gh*256 + cc*16];
  short8 o0, o1;
#pragma unroll
  for (int e = 0; e < 8; ++e) {
    int c = cc*16 + e;
    o0[e] = (short)f2bf(Ob[c>>6][c&63][i]);
    int c2 = c + 8;
    o1[e] = (short)f2bf(Ob[c2>>6][c2&63][i]);
  }
  *(short8*)dst = o0;
  *(short8*)(dst + 8) = o1;
}

// ---------------- out GEMM: AO(8192x512)bf16 @ Wout^T + bout -> fp32 ----------------
__global__ __launch_bounds__(256, 2) void out_gemm(
    const unsigned short* __restrict__ A, const unsigned short* __restrict__ Bt,
    const float* __restrict__ bout, float* __restrict__ out) {
  __shared__ unsigned short lA[128*32];
  __shared__ unsigned short lB[128*32];
  int bid = blockIdx.x;
  int tm = bid & 63, tn = bid >> 6;           // 64 x 4
  int m0 = tm * 128, n0 = tn * 128;
  int tid = threadIdx.x, lane = tid & 63, w = tid >> 6;
  int lrow = lane & 15, lgrp = lane >> 4;
  int wr = w >> 1, wc = w & 1;
  int r0 = tid >> 2, c0 = tid & 3;
  float4_ acc[4][4];
#pragma unroll
  for (int mi = 0; mi < 4; ++mi)
#pragma unroll
    for (int ni = 0; ni < 4; ++ni) acc[mi][ni] = (float4_){0.f,0.f,0.f,0.f};

  for (int k0 = 0; k0 < 512; k0 += 32) {
    short8 a0 = *(const short8*)&A[(m0 + r0)*512 + k0 + c0*8];
    short8 a1 = *(const short8*)&A[(m0 + 64 + r0)*512 + k0 + c0*8];
    short8 b0 = *(const short8*)&Bt[(n0 + r0)*512 + k0 + c0*8];
    short8 b1 = *(const short8*)&Bt[(n0 + 64 + r0)*512 + k0 + c0*8];
    __syncthreads();
    *(short8*)&lA[tid*8] = a0; *(short8*)&lA[(tid+256)*8] = a1;
    *(short8*)&lB[tid*8] = b0; *(short8*)&lB[(tid+256)*8] = b1;
    __syncthreads();
    short8 af[4], bfr[4];
#pragma unroll
    for (int mi = 0; mi < 4; ++mi) af[mi]  = *(const short8*)&lA[(wr*64 + mi*16 + lrow)*32 + lgrp*8];
#pragma unroll
    for (int ni = 0; ni < 4; ++ni) bfr[ni] = *(const short8*)&lB[(wc*64 + ni*16 + lrow)*32 + lgrp*8];
#pragma unroll
    for (int mi = 0; mi < 4; ++mi)
#pragma unroll
      for (int ni = 0; ni < 4; ++ni)
        acc[mi][ni] = __builtin_amdgcn_mfma_f32_16x16x32_bf16(af[mi], bfr[ni], acc[mi][ni], 0, 0, 0);
  }
#pragma unroll
  for (int mi = 0; mi < 4; ++mi)
#pragma unroll
    for (int ni = 0; ni < 4; ++ni) {
      int col = n0 + wc*64 + ni*16 + lrow;
      float bb = bout[col];
#pragma unroll
      for (int r = 0; r < 4; ++r) {
        int row = m0 + wr*64 + mi*16 + lgrp*4 + r;
        out[row*512 + col] = acc[mi][ni][r] + bb;
      }
    }
}

extern "C" void kernel_launch(void* const* d_in, const int* in_sizes, int n_in,
                              void* d_out, int out_size, void* d_ws, size_t ws_size,
                              hipStream_t stream) {
  (void)in_sizes; (void)n_in; (void)out_size; (void)ws_size;
  const float* x     = (const float*)d_in[0];
  const float* gamma = (const float*)d_in[1];
  const float* beta  = (const float*)d_in[2];
  const float* Wq    = (const float*)d_in[3];
  const float* Wkv   = (const float*)d_in[4];
  const float* mixp  = (const float*)d_in[5];
  const float* mixq  = (const float*)d_in[6];
  const float* Wout  = (const float*)d_in[7];
  const float* bout  = (const float*)d_in[8];
  float* out = (float*)d_out;

  unsigned short* xn  = (unsigned short*)d_ws;      // 4,194,304 bf16
  unsigned short* wt  = xn  + 4194304;              // 786,432 bf16
  unsigned short* wot = wt  + 786432;               // 262,144 bf16
  unsigned short* Qs  = wot + 262144;               // 4,194,304 bf16 (b,h,n,64)
  unsigned short* Kb  = Qs  + 4194304;              // 4,194,304 bf16 (b,h,n,64)
  _Float16*       Vt  = (_Float16*)(Kb + 4194304);  // 4,194,304 f16  (b,h,64,n)
  unsigned short* AO  = (unsigned short*)(Vt + 4194304); // 4,194,304 bf16 (b,n,512)
  unsigned int*   mqp = (unsigned int*)(AO + 4194304);   // 32 u32
  float*          ml  = (float*)(mqp + 32);              // 262,144 f32 (2 halves)
  float*          mm  = ml + 262144;                     // 65,536 f32

  ln_kernel<<<2048, 256, 0, stream>>>(x, gamma, beta, xn);
  wconv<<<4097, 256, 0, stream>>>(Wq, Wkv, Wout, mixq, wt, wot, mqp);
  qkv_gemm<<<768, 256, 0, stream>>>(xn, wt, Qs, Kb, Vt);
  attn1<<<1024, 256, 0, stream>>>(Qs, Kb, mixp, ml);
  attn1m<<<256, 256, 0, stream>>>(ml, mm);
  attn2<<<1024, 256, 0, stream>>>(Qs, Kb, Vt, mixp, mqp, mm, AO);
  out_gemm<<<256, 256, 0, stream>>>(AO, wot, bout, out);
}

// Round 5
// 580.822 us; speedup vs baseline: 1.7869x; 1.7869x over previous
//
#include <hip/hip_runtime.h>

using short4_ = short     __attribute__((ext_vector_type(4)));
using short8  = short     __attribute__((ext_vector_type(8)));
using half2v  = _Float16  __attribute__((ext_vector_type(2)));
using half4   = _Float16  __attribute__((ext_vector_type(4)));
using float2_ = float     __attribute__((ext_vector_type(2)));
using float4_ = float     __attribute__((ext_vector_type(4)));

__device__ __forceinline__ unsigned short f2bf(float f) {
  union { float f; unsigned u; } v; v.f = f;
  unsigned r = v.u + 0x7fffu + ((v.u >> 16) & 1u);
  return (unsigned short)(r >> 16);
}
__device__ __forceinline__ float sgprf(float x) {
  return __int_as_float(__builtin_amdgcn_readfirstlane(__float_as_int(x)));
}
__device__ __forceinline__ half2v pkrtz(float a, float b) {
  return __builtin_bit_cast(half2v, __builtin_amdgcn_cvt_pkrtz(a, b));
}
// LDS-drain + barrier as one unit; does NOT drain vmcnt (prefetch survives).
__device__ __forceinline__ void bar_lds() {
  asm volatile("s_waitcnt lgkmcnt(0)\ns_barrier" ::: "memory");
}

// ---------------- LayerNorm: x fp32 (8192x512) -> xn bf16 ----------------
__global__ __launch_bounds__(256, 4) void ln_kernel(
    const float* __restrict__ x, const float* __restrict__ gamma,
    const float* __restrict__ beta, unsigned short* __restrict__ xn) {
  int w = threadIdx.x >> 6, lane = threadIdx.x & 63;
  int row = blockIdx.x * 4 + w;
  const float4_* xr = (const float4_*)(x + row * 512);
  float4_ v0 = xr[lane * 2], v1 = xr[lane * 2 + 1];
  float s = 0.f, ss = 0.f;
#pragma unroll
  for (int e = 0; e < 4; ++e) { s += v0[e] + v1[e]; ss += v0[e]*v0[e] + v1[e]*v1[e]; }
#pragma unroll
  for (int off = 1; off < 64; off <<= 1) { s += __shfl_xor(s, off); ss += __shfl_xor(ss, off); }
  float mu = s * (1.f/512.f);
  float var = ss * (1.f/512.f) - mu*mu;
  float rs = rsqrtf(var + 1e-5f);
  const float4_* gp = (const float4_*)gamma;
  const float4_* bp = (const float4_*)beta;
  float4_ g0 = gp[lane*2], g1 = gp[lane*2+1], b0 = bp[lane*2], b1 = bp[lane*2+1];
  short8 pk;
#pragma unroll
  for (int e = 0; e < 4; ++e) {
    pk[e]   = (short)f2bf((v0[e]-mu)*rs*g0[e] + b0[e]);
    pk[e+4] = (short)f2bf((v1[e]-mu)*rs*g1[e] + b1[e]);
  }
  *(short8*)&xn[row*512 + lane*8] = pk;
}

// ------------- weights fp32 -> bf16 transposed (B^T layouts) -------------
__global__ __launch_bounds__(256, 4) void wconv(
    const float* __restrict__ Wq, const float* __restrict__ Wkv,
    const float* __restrict__ Wout,
    unsigned short* __restrict__ wt, unsigned short* __restrict__ wot) {
  int t = blockIdx.x * 256 + threadIdx.x;
  if (t < 786432) {
    int k = t / 1536, n = t % 1536;
    float v = (n < 512) ? Wq[k*512 + n] * 0.125f : Wkv[k*1024 + (n - 512)];
    wt[n*512 + k] = f2bf(v);
  } else {
    int t2 = t - 786432;
    int k = t2 >> 9, n = t2 & 511;
    wot[n*512 + k] = f2bf(Wout[k*512 + n]);
  }
}

// ---------------- QKV GEMM: xn(8192x512) @ Wt^T -> Q,K (bf16 b,h,n,64), V^T (f16 b,h,64,n)
__global__ __launch_bounds__(256, 2) void qkv_gemm(
    const unsigned short* __restrict__ A, const unsigned short* __restrict__ Bt,
    unsigned short* __restrict__ Qs, unsigned short* __restrict__ Kb,
    _Float16* __restrict__ Vt) {
  __shared__ unsigned short lA[128*32];
  __shared__ unsigned short lB[128*32];
  int bid = blockIdx.x;
  int tm = bid & 63, tn = bid >> 6;           // 64 x 12
  int m0 = tm * 128, n0 = tn * 128;
  int tid = threadIdx.x, lane = tid & 63, w = tid >> 6;
  int lrow = lane & 15, lgrp = lane >> 4;
  int wr = w >> 1, wc = w & 1;
  int r0 = tid >> 2, c0 = tid & 3;
  float4_ acc[4][4];
#pragma unroll
  for (int mi = 0; mi < 4; ++mi)
#pragma unroll
    for (int ni = 0; ni < 4; ++ni) acc[mi][ni] = (float4_){0.f,0.f,0.f,0.f};

  for (int k0 = 0; k0 < 512; k0 += 32) {
    short8 a0 = *(const short8*)&A[(m0 + r0)*512 + k0 + c0*8];
    short8 a1 = *(const short8*)&A[(m0 + 64 + r0)*512 + k0 + c0*8];
    short8 b0 = *(const short8*)&Bt[(n0 + r0)*512 + k0 + c0*8];
    short8 b1 = *(const short8*)&Bt[(n0 + 64 + r0)*512 + k0 + c0*8];
    __syncthreads();
    *(short8*)&lA[tid*8] = a0; *(short8*)&lA[(tid+256)*8] = a1;
    *(short8*)&lB[tid*8] = b0; *(short8*)&lB[(tid+256)*8] = b1;
    __syncthreads();
    short8 af[4], bfr[4];
#pragma unroll
    for (int mi = 0; mi < 4; ++mi) af[mi]  = *(const short8*)&lA[(wr*64 + mi*16 + lrow)*32 + lgrp*8];
#pragma unroll
    for (int ni = 0; ni < 4; ++ni) bfr[ni] = *(const short8*)&lB[(wc*64 + ni*16 + lrow)*32 + lgrp*8];
#pragma unroll
    for (int mi = 0; mi < 4; ++mi)
#pragma unroll
      for (int ni = 0; ni < 4; ++ni)
        acc[mi][ni] = __builtin_amdgcn_mfma_f32_16x16x32_bf16(af[mi], bfr[ni], acc[mi][ni], 0, 0, 0);
  }
#pragma unroll
  for (int mi = 0; mi < 4; ++mi) {
#pragma unroll
    for (int ni = 0; ni < 4; ++ni) {
      int col = n0 + wc*64 + ni*16 + lrow;
#pragma unroll
      for (int r = 0; r < 4; ++r) {
        int row = m0 + wr*64 + mi*16 + lgrp*4 + r;
        float v = acc[mi][ni][r];
        int b = row >> 11, i = row & 2047;
        if (col < 1024) {
          unsigned short* dst = (col < 512) ? Qs : Kb;
          int c = col & 511;
          dst[(((b<<3) + (c>>6))*2048 + i)*64 + (c & 63)] = f2bf(v);
        } else {
          int c = col - 1024;
          Vt[(((b<<3) + (c>>6))*64 + (c & 63))*2048 + i] = (_Float16)v;
        }
      }
    }
  }
}

// ---------------- fused talking-heads attention, head-per-wave ----------------
// grid 512 = (4 b x 128 i-tiles), 512 threads = 8 waves; wave w = head w.
// pass1: S^T=mfma(K_w,Q_w); f16 S-exchange in LDS; premix col w; online (m,l).
// pass2: recompute S; exchange; premix; p=exp(s-mm); f16 P-exchange; postmix col w;
//        PV with V_w. K register-prefetched; barriers don't drain vmcnt.
__global__ __launch_bounds__(512, 4) void attn_f(
    const unsigned short* __restrict__ Qs, const unsigned short* __restrict__ Kb,
    const _Float16* __restrict__ Vt, const float* __restrict__ mixp,
    const float* __restrict__ mixq, unsigned short* __restrict__ AO) {
  __shared__ unsigned long long sbuf[2][8][64];
  __shared__ unsigned long long pbuf[2][8][64];
  int bid = blockIdx.x;
  int b = (bid & 7) >> 1;                         // same-b blocks share an XCD pair
  int it = ((bid >> 3) << 1) | (bid & 1);
  int i0 = it << 4;
  int tid = threadIdx.x, w = tid >> 6, lane = tid & 63;
  int lrow = lane & 15, lgrp = lane >> 4;
  int bh = (b << 3) + w;

  // mix columns for this wave, in SGPRs
  float mp[8];
#pragma unroll
  for (int h = 0; h < 8; ++h) mp[h] = sgprf(mixp[h*8 + w]);
  unsigned mqs[8];
#pragma unroll
  for (int g = 0; g < 8; ++g) {
    float v = mixq[g*8 + w];
    half2v h2 = pkrtz(v, v);
    mqs[g] = (unsigned)__builtin_amdgcn_readfirstlane((int)__builtin_bit_cast(unsigned, h2));
  }

  // Q fragments (B-operand: col=i, k=d), persistent
  const unsigned short* qp = &Qs[(bh*2048 + i0 + lrow)*64 + lgrp*8];
  short8 qf0 = *(const short8*)qp;
  short8 qf1 = *(const short8*)(qp + 32);

  const unsigned short* kbase = &Kb[(bh*2048 + lrow)*64 + lgrp*8];
  const _Float16*       vbase = &Vt[(bh*64 + lrow)*2048 + lgrp*4];

  // prefetch K tile 0
  short8 ka0 = *(const short8*)kbase;
  short8 ka1 = *(const short8*)(kbase + 32);
  short8 kb0, kb1;

  float m_ = -1e30f, l_ = 0.f;

  // ---------------- PASS 1 ----------------
  auto p1body = [&](int t, short8& c0, short8& c1, short8& n0, short8& n1) {
    const unsigned short* kn = kbase + (((t + 1) & 127) << 10);
    n0 = *(const short8*)kn;
    n1 = *(const short8*)(kn + 32);
    float4_ S = {0.f,0.f,0.f,0.f};
    S = __builtin_amdgcn_mfma_f32_16x16x32_bf16(c0, qf0, S, 0, 0, 0);
    S = __builtin_amdgcn_mfma_f32_16x16x32_bf16(c1, qf1, S, 0, 0, 0);
    unsigned lo = __builtin_bit_cast(unsigned, pkrtz(S[0], S[1]));
    unsigned hi = __builtin_bit_cast(unsigned, pkrtz(S[2], S[3]));
    sbuf[t & 1][w][lane] = (unsigned long long)lo | ((unsigned long long)hi << 32);
    bar_lds();
    float s0 = 0.f, s1 = 0.f, s2 = 0.f, s3 = 0.f;
#pragma unroll
    for (int h = 0; h < 8; ++h) {
      unsigned long long u = sbuf[t & 1][h][lane];
      half2v l2 = __builtin_bit_cast(half2v, (unsigned)u);
      half2v h2 = __builtin_bit_cast(half2v, (unsigned)(u >> 32));
      s0 = fmaf(mp[h], (float)l2[0], s0);
      s1 = fmaf(mp[h], (float)l2[1], s1);
      s2 = fmaf(mp[h], (float)h2[0], s2);
      s3 = fmaf(mp[h], (float)h2[1], s3);
    }
    float tm = fmaxf(fmaxf(s0, s1), fmaxf(s2, s3));
    float mn = fmaxf(m_, tm);
    l_ = l_*__expf(m_-mn) + __expf(s0-mn) + __expf(s1-mn) + __expf(s2-mn) + __expf(s3-mn);
    m_ = mn;
  };
  for (int tt = 0; tt < 64; ++tt) {
    p1body(2*tt,     ka0, ka1, kb0, kb1);
    p1body(2*tt + 1, kb0, kb1, ka0, ka1);
  }
  // merge across the 4 lane-groups (disjoint j)
#pragma unroll
  for (int off = 16; off < 64; off <<= 1) {
    float om = __shfl_xor(m_, off);
    float ol = __shfl_xor(l_, off);
    float mn = fmaxf(m_, om);
    l_ = l_*__expf(m_-mn) + ol*__expf(om-mn);
    m_ = mn;
  }
  float mm = m_ + __logf(l_);      // exp(s - mm) is exactly normalized

  // ---------------- PASS 2 ----------------
  float4_ ot0 = {0.f,0.f,0.f,0.f}, ot1 = ot0, ot2 = ot0, ot3 = ot0;
  auto p2body = [&](int t, short8& c0, short8& c1, short8& n0, short8& n1) {
    const unsigned short* kn = kbase + (((t + 1) & 127) << 10);
    n0 = *(const short8*)kn;
    n1 = *(const short8*)(kn + 32);
    const _Float16* vb = vbase + (t << 4);
    half4 vf0 = *(const half4*)vb;
    half4 vf1 = *(const half4*)(vb + 16*2048);
    half4 vf2 = *(const half4*)(vb + 32*2048);
    half4 vf3 = *(const half4*)(vb + 48*2048);
    float4_ S = {0.f,0.f,0.f,0.f};
    S = __builtin_amdgcn_mfma_f32_16x16x32_bf16(c0, qf0, S, 0, 0, 0);
    S = __builtin_amdgcn_mfma_f32_16x16x32_bf16(c1, qf1, S, 0, 0, 0);
    unsigned lo = __builtin_bit_cast(unsigned, pkrtz(S[0], S[1]));
    unsigned hi = __builtin_bit_cast(unsigned, pkrtz(S[2], S[3]));
    sbuf[t & 1][w][lane] = (unsigned long long)lo | ((unsigned long long)hi << 32);
    bar_lds();
    float s0 = 0.f, s1 = 0.f, s2 = 0.f, s3 = 0.f;
#pragma unroll
    for (int h = 0; h < 8; ++h) {
      unsigned long long u = sbuf[t & 1][h][lane];
      half2v l2 = __builtin_bit_cast(half2v, (unsigned)u);
      half2v h2 = __builtin_bit_cast(half2v, (unsigned)(u >> 32));
      s0 = fmaf(mp[h], (float)l2[0], s0);
      s1 = fmaf(mp[h], (float)l2[1], s1);
      s2 = fmaf(mp[h], (float)h2[0], s2);
      s3 = fmaf(mp[h], (float)h2[1], s3);
    }
    float p0 = __expf(s0 - mm), p1 = __expf(s1 - mm);
    float p2 = __expf(s2 - mm), p3 = __expf(s3 - mm);
    unsigned plo = __builtin_bit_cast(unsigned, pkrtz(p0, p1));
    unsigned phi = __builtin_bit_cast(unsigned, pkrtz(p2, p3));
    pbuf[t & 1][w][lane] = (unsigned long long)plo | ((unsigned long long)phi << 32);
    bar_lds();
    half2v A0 = (half2v)0, A1 = (half2v)0;
#pragma unroll
    for (int g = 0; g < 8; ++g) {
      unsigned long long u = pbuf[t & 1][g][lane];
      half2v l2 = __builtin_bit_cast(half2v, (unsigned)u);
      half2v h2 = __builtin_bit_cast(half2v, (unsigned)(u >> 32));
      half2v m2 = __builtin_bit_cast(half2v, mqs[g]);
      A0 += m2 * l2;
      A1 += m2 * h2;
    }
    half4 pb;
    pb[0] = A0[0]; pb[1] = A0[1]; pb[2] = A1[0]; pb[3] = A1[1];
    ot0 = __builtin_amdgcn_mfma_f32_16x16x16f16(vf0, pb, ot0, 0, 0, 0);
    ot1 = __builtin_amdgcn_mfma_f32_16x16x16f16(vf1, pb, ot1, 0, 0, 0);
    ot2 = __builtin_amdgcn_mfma_f32_16x16x16f16(vf2, pb, ot2, 0, 0, 0);
    ot3 = __builtin_amdgcn_mfma_f32_16x16x16f16(vf3, pb, ot3, 0, 0, 0);
  };
  for (int tt = 0; tt < 64; ++tt) {
    p2body(2*tt,     ka0, ka1, kb0, kb1);
    p2body(2*tt + 1, kb0, kb1, ka0, ka1);
  }

  // epilogue: O[d = dt*16 + lgrp*4 + r][i = lrow] -> AO (b, n, w*64+d) bf16
  unsigned short* ao = &AO[(b*2048 + i0 + lrow)*512 + w*64 + lgrp*4];
  float4_ ov[4] = {ot0, ot1, ot2, ot3};
#pragma unroll
  for (int dt = 0; dt < 4; ++dt) {
    short4_ pk;
#pragma unroll
    for (int r = 0; r < 4; ++r) pk[r] = (short)f2bf(ov[dt][r]);
    *(short4_*)(ao + dt*16) = pk;
  }
}

// ---------------- out GEMM: AO(8192x512)bf16 @ Wout^T + bout -> fp32 ----------------
__global__ __launch_bounds__(256, 2) void out_gemm(
    const unsigned short* __restrict__ A, const unsigned short* __restrict__ Bt,
    const float* __restrict__ bout, float* __restrict__ out) {
  __shared__ unsigned short lA[128*32];
  __shared__ unsigned short lB[128*32];
  int bid = blockIdx.x;
  int tm = bid & 63, tn = bid >> 6;           // 64 x 4
  int m0 = tm * 128, n0 = tn * 128;
  int tid = threadIdx.x, lane = tid & 63, w = tid >> 6;
  int lrow = lane & 15, lgrp = lane >> 4;
  int wr = w >> 1, wc = w & 1;
  int r0 = tid >> 2, c0 = tid & 3;
  float4_ acc[4][4];
#pragma unroll
  for (int mi = 0; mi < 4; ++mi)
#pragma unroll
    for (int ni = 0; ni < 4; ++ni) acc[mi][ni] = (float4_){0.f,0.f,0.f,0.f};

  for (int k0 = 0; k0 < 512; k0 += 32) {
    short8 a0 = *(const short8*)&A[(m0 + r0)*512 + k0 + c0*8];
    short8 a1 = *(const short8*)&A[(m0 + 64 + r0)*512 + k0 + c0*8];
    short8 b0 = *(const short8*)&Bt[(n0 + r0)*512 + k0 + c0*8];
    short8 b1 = *(const short8*)&Bt[(n0 + 64 + r0)*512 + k0 + c0*8];
    __syncthreads();
    *(short8*)&lA[tid*8] = a0; *(short8*)&lA[(tid+256)*8] = a1;
    *(short8*)&lB[tid*8] = b0; *(short8*)&lB[(tid+256)*8] = b1;
    __syncthreads();
    short8 af[4], bfr[4];
#pragma unroll
    for (int mi = 0; mi < 4; ++mi) af[mi]  = *(const short8*)&lA[(wr*64 + mi*16 + lrow)*32 + lgrp*8];
#pragma unroll
    for (int ni = 0; ni < 4; ++ni) bfr[ni] = *(const short8*)&lB[(wc*64 + ni*16 + lrow)*32 + lgrp*8];
#pragma unroll
    for (int mi = 0; mi < 4; ++mi)
#pragma unroll
      for (int ni = 0; ni < 4; ++ni)
        acc[mi][ni] = __builtin_amdgcn_mfma_f32_16x16x32_bf16(af[mi], bfr[ni], acc[mi][ni], 0, 0, 0);
  }
#pragma unroll
  for (int mi = 0; mi < 4; ++mi)
#pragma unroll
    for (int ni = 0; ni < 4; ++ni) {
      int col = n0 + wc*64 + ni*16 + lrow;
      float bb = bout[col];
#pragma unroll
      for (int r = 0; r < 4; ++r) {
        int row = m0 + wr*64 + mi*16 + lgrp*4 + r;
        out[row*512 + col] = acc[mi][ni][r] + bb;
      }
    }
}

extern "C" void kernel_launch(void* const* d_in, const int* in_sizes, int n_in,
                              void* d_out, int out_size, void* d_ws, size_t ws_size,
                              hipStream_t stream) {
  (void)in_sizes; (void)n_in; (void)out_size; (void)ws_size;
  const float* x     = (const float*)d_in[0];
  const float* gamma = (const float*)d_in[1];
  const float* beta  = (const float*)d_in[2];
  const float* Wq    = (const float*)d_in[3];
  const float* Wkv   = (const float*)d_in[4];
  const float* mixp  = (const float*)d_in[5];
  const float* mixq  = (const float*)d_in[6];
  const float* Wout  = (const float*)d_in[7];
  const float* bout  = (const float*)d_in[8];
  float* out = (float*)d_out;

  unsigned short* xn  = (unsigned short*)d_ws;      // 4,194,304 bf16
  unsigned short* wt  = xn  + 4194304;              // 786,432 bf16
  unsigned short* wot = wt  + 786432;               // 262,144 bf16
  unsigned short* Qs  = wot + 262144;               // 4,194,304 bf16 (b,h,n,64)
  unsigned short* Kb  = Qs  + 4194304;              // 4,194,304 bf16 (b,h,n,64)
  _Float16*       Vt  = (_Float16*)(Kb + 4194304);  // 4,194,304 f16  (b,h,64,n)
  unsigned short* AO  = (unsigned short*)(Vt + 4194304); // 4,194,304 bf16 (b,n,512)

  ln_kernel<<<2048, 256, 0, stream>>>(x, gamma, beta, xn);
  wconv<<<4096, 256, 0, stream>>>(Wq, Wkv, Wout, wt, wot);
  qkv_gemm<<<768, 256, 0, stream>>>(xn, wt, Qs, Kb, Vt);
  attn_f<<<512, 512, 0, stream>>>(Qs, Kb, Vt, mixp, mixq, AO);
  out_gemm<<<256, 256, 0, stream>>>(AO, wot, bout, out);
}